// Round 2
// baseline (845.979 us; speedup 1.0000x reference)
//
#include <hip/hip_runtime.h>
#include <math.h>

#define DIM       32
#define N_NODES   100000
#define N_EDGES   1600000
#define L0        0.1f
#define NBUCKET   8
#define NODES_PER_BUCKET 12500   // 100000 / 8, grad slice = 12500*128B = 1.6 MB < 4 MiB XCD L2

// ---------------------------------------------------------------------------
// Phase A: per-edge factor + energy.  One wave = 2 edges; lane = 32*half + d.
// Dot product in f32 (threshold 1.19e5, we were at 1052 with f64 — headroom),
// clamp emulated bit-exactly vs the f32 reference: fminf(inner, -1.0000001f).
// ---------------------------------------------------------------------------
__global__ __launch_bounds__(256) void factor_energy_kernel(
    const float* __restrict__ x,
    const int*   __restrict__ edges,
    float*       __restrict__ factor_ws,
    float*       __restrict__ out)        // out[0] = energy
{
    const int tid    = threadIdx.x;
    const int lane   = tid & 63;
    const int d      = lane & 31;
    const int half   = lane >> 5;
    const int waveId = (blockIdx.x * blockDim.x + tid) >> 6;
    const int nWaves = (gridDim.x * blockDim.x) >> 6;

    double energy = 0.0;

    for (int e0 = waveId * 2; e0 < N_EDGES; e0 += nWaves * 2) {
        const int  e      = e0 + half;
        const bool active = (e < N_EDGES);

        float xu = 0.0f, xv = 0.0f;
        if (active) {
            const int2 ev = ((const int2*)edges)[e];
            xu = x[ev.x * DIM + d];       // contiguous 128B row per half-wave
            xv = x[ev.y * DIM + d];
        }

        float p = xu * xv;
        if (d == 0) p = -p;
        #pragma unroll
        for (int off = 16; off; off >>= 1)
            p += __shfl_xor(p, off, 32);

        // clamp: inner = min(inner, -1-1e-7); zm1 = -inner - 1 (exact for |inner|~1)
        float inner = fminf(p, -1.0000001f);
        float zm1   = -inner - 1.0f;
        // s = sqrt(inner^2-1) = sqrt(zm1*(zm1+2));  dist = acosh(-inner) = log1p(zm1+s)
        float s      = sqrtf(zm1 * (zm1 + 2.0f));
        float dist   = log1pf(zm1 + s);
        float delta  = dist - L0;
        float factor = -delta / (s + 1e-9f);       // K = 1

        if (active && d == 0) {
            factor_ws[e] = factor;
            energy += 0.5 * (double)delta * (double)delta;
        }
    }

    #pragma unroll
    for (int off = 32; off; off >>= 1)
        energy += __shfl_xor(energy, off, 64);

    __shared__ double s_e[4];
    if (lane == 0) s_e[tid >> 6] = energy;
    __syncthreads();
    if (tid == 0)
        atomicAdd(&out[0], (float)(s_e[0] + s_e[1] + s_e[2] + s_e[3]));
}

// ---------------------------------------------------------------------------
// Phase B: XCD-sharded scatter.  bucket = blockIdx & 7 maps (round-robin
// dispatch heuristic) each XCD to one 1.6 MB grad slice that stays L2-
// resident, so the 102.4M atomic adds become L2 hits instead of 500 MB of
// HBM writeback thrash.  Each bucket-set scans all edges (L3-served).
// ---------------------------------------------------------------------------
__global__ __launch_bounds__(256) void scatter_kernel(
    const float* __restrict__ x,
    const int*   __restrict__ edges,
    const float* __restrict__ factor_ws,
    float*       __restrict__ grad)
{
    const int tid     = threadIdx.x;
    const int lane    = tid & 63;
    const int d       = lane & 31;
    const int half    = lane >> 5;
    const int bucket  = blockIdx.x & (NBUCKET - 1);
    const int sub     = blockIdx.x >> 3;
    const int nSub    = gridDim.x >> 3;
    const int waveId  = sub * (blockDim.x >> 6) + (tid >> 6);
    const int nWaves  = nSub * (blockDim.x >> 6);
    const float Jd    = (d == 0) ? -1.0f : 1.0f;
    const int lo = bucket * NODES_PER_BUCKET;
    const int hi = lo + NODES_PER_BUCKET;

    for (int e0 = waveId * 2; e0 < N_EDGES; e0 += nWaves * 2) {
        const int e = e0 + half;
        if (e >= N_EDGES) continue;

        const int2 ev = ((const int2*)edges)[e];   // 8B, half-wave uniform
        const int  u  = ev.x, v = ev.y;
        const float f = factor_ws[e];

        if (u >= lo && u < hi) {                   // half-wave-uniform branch
            float xv = x[v * DIM + d];
            atomicAdd(&grad[u * DIM + d], f * xv * Jd);
        }
        if (v >= lo && v < hi) {
            float xu = x[u * DIM + d];
            atomicAdd(&grad[v * DIM + d], f * xu * Jd);
        }
    }
}

// ---------------------------------------------------------------------------
// Fallback (ws too small): R1's fused kernel, known-correct at 505 us.
// ---------------------------------------------------------------------------
__global__ __launch_bounds__(256) void spring_edge_kernel(
    const float* __restrict__ x,
    const int*   __restrict__ edges,
    float*       __restrict__ out)
{
    const int tid    = threadIdx.x;
    const int lane   = tid & 63;
    const int d      = lane & 31;
    const int half   = lane >> 5;
    const int waveId = (blockIdx.x * blockDim.x + tid) >> 6;
    const int nWaves = (gridDim.x * blockDim.x) >> 6;

    float* __restrict__ grad = out + 1;
    const float Jd = (d == 0) ? -1.0f : 1.0f;
    double energy = 0.0;

    for (int e0 = waveId * 2; e0 < N_EDGES; e0 += nWaves * 2) {
        const int  e      = e0 + half;
        const bool active = (e < N_EDGES);
        int u = 0, v = 0;
        float xu = 0.0f, xv = 0.0f;
        if (active) {
            u  = edges[2 * e];
            v  = edges[2 * e + 1];
            xu = x[u * DIM + d];
            xv = x[v * DIM + d];
        }
        float p = xu * xv;
        if (d == 0) p = -p;
        #pragma unroll
        for (int off = 16; off; off >>= 1)
            p += __shfl_xor(p, off, 32);

        float inner  = fminf(p, -1.0000001f);
        float zm1    = -inner - 1.0f;
        float s      = sqrtf(zm1 * (zm1 + 2.0f));
        float dist   = log1pf(zm1 + s);
        float delta  = dist - L0;
        float factor = -delta / (s + 1e-9f);

        if (active) {
            atomicAdd(&grad[u * DIM + d], factor * xv * Jd);
            atomicAdd(&grad[v * DIM + d], factor * xu * Jd);
            if (d == 0)
                energy += 0.5 * (double)delta * (double)delta;
        }
    }

    #pragma unroll
    for (int off = 32; off; off >>= 1)
        energy += __shfl_xor(energy, off, 64);

    __shared__ double s_e[4];
    if (lane == 0) s_e[tid >> 6] = energy;
    __syncthreads();
    if (tid == 0)
        atomicAdd(&out[0], (float)(s_e[0] + s_e[1] + s_e[2] + s_e[3]));
}

extern "C" void kernel_launch(void* const* d_in, const int* in_sizes, int n_in,
                              void* d_out, int out_size, void* d_ws, size_t ws_size,
                              hipStream_t stream) {
    const float* x     = (const float*)d_in[0];
    const int*   edges = (const int*)d_in[1];
    float*       out   = (float*)d_out;

    hipMemsetAsync(out, 0, (size_t)out_size * sizeof(float), stream);

    if (ws_size >= (size_t)N_EDGES * sizeof(float)) {
        float* factor_ws = (float*)d_ws;
        factor_energy_kernel<<<4096, 256, 0, stream>>>(x, edges, factor_ws, out);
        scatter_kernel<<<8192, 256, 0, stream>>>(x, edges, factor_ws, out + 1);
    } else {
        spring_edge_kernel<<<4096, 256, 0, stream>>>(x, edges, out);
    }
}